// Round 9
// baseline (283.754 us; speedup 1.0000x reference)
//
#include <hip/hip_runtime.h>
#include <math.h>

#define SCALE_L2E 0.51006972157f   // (1/sqrt(8)) * log2(e) -- softmax done in exp2 domain
#define EPSV 1e-5f

typedef __attribute__((ext_vector_type(8))) short bf16x8;
typedef __attribute__((ext_vector_type(4))) float f32x4;
typedef __attribute__((ext_vector_type(4), aligned(4))) float f32x4u;  // 4B-aligned vector load
typedef __attribute__((ext_vector_type(16))) float f32x16;
typedef __attribute__((ext_vector_type(4))) int i32x4;
typedef __attribute__((ext_vector_type(2))) int i32x2;

static __device__ __forceinline__ unsigned short bfh(float f) {
    return (unsigned short)(__builtin_bit_cast(unsigned int, f) >> 16);
}
static __device__ __forceinline__ int pack2(float lo, float hi) {
    return __builtin_amdgcn_perm(__builtin_bit_cast(unsigned int, hi),
                                 __builtin_bit_cast(unsigned int, lo), 0x07060302u);
}
#define LGKM0() __asm__ __volatile__("s_waitcnt lgkmcnt(0)" ::: "memory")
#define MFMA16(a, b, c) __builtin_amdgcn_mfma_f32_16x16x32_bf16((a), (b), (c), 0, 0, 0)

// ws layout: [0,8192) ushort wqk B-frags; [8192,40960) ushort W2ᵀ B-frags;
//            byte 81920: float bnA[64], bnB[64]
__global__ void prep_kernel(const float* __restrict__ w_qk,
                            const float* __restrict__ conv_w,
                            const float* __restrict__ conv_b,
                            const float* __restrict__ bn_g, const float* __restrict__ bn_b,
                            const float* __restrict__ bn_m, const float* __restrict__ bn_v,
                            unsigned short* __restrict__ ws) {
    int i = blockIdx.x * 256 + threadIdx.x;
    if (i < 8192) {
        int f = i >> 9, rem = i & 511, l = rem >> 3, j = rem & 7;
        int nt = f >> 1, ks = f & 1;
        int k = ks * 32 + (l >> 4) * 8 + j;
        int nn = nt * 16 + (l & 15);
        ws[i] = bfh(w_qk[k * 128 + nn]);
    } else if (i < 40960) {
        int i2 = i - 8192;
        int g = i2 >> 9, rem = i2 & 511, l = rem >> 3, j = rem & 7;
        int h = g >> 3, nt = (g >> 1) & 3, ks = g & 1;
        int c = ks * 32 + (l >> 4) * 8 + j;
        int o = nt * 16 + (l & 15);
        ws[i] = bfh(conv_w[h * 4096 + o * 64 + c]);
    } else if (i < 41024) {
        int o = i - 40960;
        float gv = bn_g[o] * rsqrtf(bn_v[o] + EPSV);
        float bb = bn_b[o] - bn_m[o] * gv;
        float cb = 0.f;
        for (int h = 0; h < 8; h++) cb += conv_b[h * 64 + o];
        float* wsf = (float*)(ws + 40960);
        wsf[o] = gv;
        wsf[64 + o] = bb + cb * gv;
    }
}

// R9: r8 + COALESCED FULL-LINE x INGEST. Post-mortems r0-r8 (MEASURED): dur
// invariant ~98us while occupancy 27-39%, chain length 4x, VALU work -30%,
// traffic 98-153MB all varied. Not compute / BW / occupancy bound. The ONE
// never-varied invariant: x ingested via scalar stride-6400 loads (8 lines per
// wave instr, 4B/lane) and re-read in the epilogue => MLP-limited memory
// latency: ~25 lines in flight/CU x 64B / ~375ns ~= 1.2-1.5 TB/s = observed
// hbm_gbps every round. Fix: block-cooperative float4 ingest (each instr = 16
// FULLY-consumed 64B lines; lane c=wv*16+(lane&15), p=lane>>4), staged to LDS
// xraw[64][28]f32 (stride-28 -> <=2-way banks). LN stats, frag build, AND the
// epilogue residual read from LDS (second global x read eliminated).
// Body unchanged from r8 (block=tile, wave=head-pair, LDS reduce).
// LDS: [0,36864) 4x9216 wave-private (r8 layout; reduce buf aliases after sync)
//      [36864,44032) xraw f32[64][28]; [44032,44160) mus; [44160,44288) rss.
// 44288 B -> 3 blocks/CU (12 waves/CU ~= r8's measured 39%).
// Spill tripwire (MEASURED r1/r2/r6): FETCH > 75 MB => revert.
// PRE-COMMIT: if dur lands 95-105us again (no spill), declare structural floor.
__global__ __launch_bounds__(256, 2)
void sagc_kernel(const float* __restrict__ x,
                 const float* __restrict__ ln_g, const float* __restrict__ ln_b,
                 const float* __restrict__ b_qk,
                 const float* __restrict__ topo,
                 const unsigned short* __restrict__ ws,
                 float* __restrict__ out)
{
    __shared__ __align__(16) unsigned char smem[44288];
    const int tid = threadIdx.x;
    const int lane = tid & 63, wv = tid >> 6;
    const int l15 = lane & 15, quad = lane >> 4;
    const int r32 = lane & 31, hi = lane >> 5;

    unsigned char* my = smem + wv * 9216;
    unsigned short* qbuf = (unsigned short*)my;            // [32][24] u16
    unsigned short* kbuf = (unsigned short*)(my + 1536);
    unsigned char*  fwb  = my;                             // FWT swizzled (overlays q/k)
    unsigned char*  pb0  = my + 4096;                      // P0 [32][40] u16
    unsigned char*  pb1  = my + 6656;                      // P1

    float* xrawF = (float*)(smem + 36864);                 // [64][28] f32
    float* mus   = (float*)(smem + 44032);                 // [25] (+pad)
    float* rss   = (float*)(smem + 44160);                 // [25] (+pad)

    const unsigned short* wqk = ws;
    const unsigned short* w2f = ws + 8192;
    const float* bnA = (const float*)(ws + 40960);
    const float* bnB = bnA + 64;

    const int tile = blockIdx.x;                           // one tile per block
    const int n = tile >> 8, t = tile & 255;
    const float* xg = x + (size_t)n * 409600 + (size_t)t * 25;   // + c*6400 + v
    float* og = out + (size_t)n * 409600 + (size_t)t * 25;

    const int hp = wv;                                     // this wave's head-pair

    // ---- coalesced x ingest: wave wv loads channels [16wv,16wv+16) ----
    // Each f32x4 instr: 16 channels x 16B consecutive = 16 fully-used 64B lines.
    {
        const int cl = lane & 15, p = lane >> 4;
        const int c = wv * 16 + cl;
        const float* xc = xg + (size_t)c * 6400;
        float* xrow = xrawF + c * 28;
        f32x4u a = *(const f32x4u*)(xc + 4 * p);           // v = 4p..4p+3 (0..15)
        *(f32x4*)(xrow + 4 * p) = (f32x4){a[0], a[1], a[2], a[3]};
        if (p < 2) {
            f32x4u b = *(const f32x4u*)(xc + 16 + 4 * p);  // v = 16..23
            *(f32x4*)(xrow + 16 + 4 * p) = (f32x4){b[0], b[1], b[2], b[3]};
        } else if (p == 2) {
            xrow[24] = xc[24];                             // v = 24
        }
    }
    __syncthreads();

    // ---- LN stats from LDS: wave wv -> v in [8wv,8wv+8); part-rotated reads ----
    {
        const int vst = wv * 8 + (lane >> 3);
        const int part = lane & 7;
        const int vv = (vst < 25) ? vst : 0;
        float s = 0.f, ss = 0.f;
        #pragma unroll
        for (int j = 0; j < 8; j++) {
            int jj = (j + part) & 7;                       // bank-spread rotation
            float a = xrawF[(part * 8 + jj) * 28 + vv];
            s += a; ss += a * a;
        }
        s  += __shfl_xor(s, 1);  s  += __shfl_xor(s, 2);  s  += __shfl_xor(s, 4);
        ss += __shfl_xor(ss, 1); ss += __shfl_xor(ss, 2); ss += __shfl_xor(ss, 4);
        if (vst < 25 && part == 0) {
            float mu = s * 0.015625f;
            mus[vst] = mu;
            rss[vst] = rsqrtf(ss * 0.015625f - mu * mu + EPSV);
        }
    }
    __syncthreads();

    // ---- frag build from LDS (quad-rotated reads; dead rows v>=25 -> xa=0) ----
    bf16x8 xa[2][2], yna[2][2];
    {
        float muv[2], rsv[2], xfv[2][2][8];
        #pragma unroll
        for (int mt = 0; mt < 2; mt++) {
            int v = mt * 16 + l15;
            bool ok = (v < 25);
            int vr = ok ? v : 0;
            muv[mt] = mus[vr];
            rsv[mt] = rss[vr];
            #pragma unroll
            for (int ks = 0; ks < 2; ks++)
                #pragma unroll
                for (int j = 0; j < 8; j++) {
                    int jj = (j + 2 * quad) & 7;           // bank-spread rotation
                    int c = ks * 32 + quad * 8 + jj;
                    xfv[mt][ks][jj] = ok ? xrawF[c * 28 + v] : 0.f;
                }
        }
        #pragma unroll
        for (int ks = 0; ks < 2; ks++) {
            f32x4 ga = *(const f32x4*)&ln_g[ks * 32 + quad * 8];
            f32x4 gb = *(const f32x4*)&ln_g[ks * 32 + quad * 8 + 4];
            f32x4 ba = *(const f32x4*)&ln_b[ks * 32 + quad * 8];
            f32x4 bb = *(const f32x4*)&ln_b[ks * 32 + quad * 8 + 4];
            #pragma unroll
            for (int mt = 0; mt < 2; mt++) {
                i32x4 px, py;
                #pragma unroll
                for (int q = 0; q < 4; q++) {
                    float a0 = xfv[mt][ks][2 * q], a1 = xfv[mt][ks][2 * q + 1];
                    float g0 = (q < 2) ? ga[2 * q] : gb[2 * q - 4];
                    float g1 = (q < 2) ? ga[2 * q + 1] : gb[2 * q - 3];
                    float b0 = (q < 2) ? ba[2 * q] : bb[2 * q - 4];
                    float b1 = (q < 2) ? ba[2 * q + 1] : bb[2 * q - 3];
                    float y0 = (a0 - muv[mt]) * rsv[mt] * g0 + b0;
                    float y1 = (a1 - muv[mt]) * rsv[mt] * g1 + b1;
                    px[q] = pack2(a0, a1);
                    py[q] = pack2(y0, y1);
                }
                xa[mt][ks]  = __builtin_bit_cast(bf16x8, px);
                yna[mt][ks] = __builtin_bit_cast(bf16x8, py);
            }
        }
    }

    f32x4 acc[2][4];
    #pragma unroll
    for (int mt = 0; mt < 2; mt++)
        #pragma unroll
        for (int nt = 0; nt < 4; nt++)
            acc[mt][nt] = (f32x4){0.f, 0.f, 0.f, 0.f};

    const f32x4 z4 = {0.f, 0.f, 0.f, 0.f};
    const bf16x8 z8 = {0, 0, 0, 0, 0, 0, 0, 0};
    const f32x16 z16 = {0.f,0.f,0.f,0.f,0.f,0.f,0.f,0.f,0.f,0.f,0.f,0.f,0.f,0.f,0.f,0.f};

    // FWT swizzle constants (16B block ^= (l15>>2)&3)
    const int sw4 = (l15 >> 2) & 3;
    unsigned char* w0p = fwb + ((((quad >> 1) ^ sw4)) << 4) + (quad & 1) * 8;
    unsigned char* w1p = fwb + (((((quad >> 1) ^ sw4)) ^ 2) << 4) + (quad & 1) * 8;
    unsigned char* brp = fwb + l15 * 64 + ((quad ^ sw4) << 4);

    const int uc = (r32 < 25) ? r32 : 24;   // clamped topo row

    // in-register softmax + P store (verified r5 layout). dd: lane r32 = row u;
    // v(r) = (r&3)+8*(r>>2)+4*hi.
    auto softmax_store = [&](f32x16& dd, const float* tp, unsigned char* Pb) {
        dd[12] = hi ? -3e30f : dd[12];
        dd[13] = -3e30f; dd[14] = -3e30f; dd[15] = -3e30f;
        float t8[8];
        #pragma unroll
        for (int r = 0; r < 8; r++) t8[r] = fmaxf(dd[r], dd[r + 8]);
        #pragma unroll
        for (int r = 0; r < 4; r++) t8[r] = fmaxf(t8[r], t8[r + 4]);
        float m = fmaxf(fmaxf(t8[0], t8[1]), fmaxf(t8[2], t8[3]));
        m = fmaxf(m, __shfl_xor(m, 32));
        float s0 = 0.f, s1 = 0.f, s2 = 0.f, s3 = 0.f;
        #pragma unroll
        for (int r = 0; r < 16; r += 4) {
            dd[r]     = __builtin_amdgcn_exp2f(dd[r] - m);     s0 += dd[r];
            dd[r + 1] = __builtin_amdgcn_exp2f(dd[r + 1] - m); s1 += dd[r + 1];
            dd[r + 2] = __builtin_amdgcn_exp2f(dd[r + 2] - m); s2 += dd[r + 2];
            dd[r + 3] = __builtin_amdgcn_exp2f(dd[r + 3] - m); s3 += dd[r + 3];
        }
        float s = (s0 + s1) + (s2 + s3);
        s += __shfl_xor(s, 32);
        float inv = __builtin_amdgcn_rcpf(s);
        #pragma unroll
        for (int r = 0; r < 16; r++) dd[r] = dd[r] * inv * tp[r];
        if (r32 < 25) {
            unsigned char* rowp = Pb + r32 * 80 + hi * 8;
            *(i32x2*)(rowp +  0) = (i32x2){pack2(dd[0], dd[1]),   pack2(dd[2], dd[3])};
            *(i32x2*)(rowp + 16) = (i32x2){pack2(dd[4], dd[5]),   pack2(dd[6], dd[7])};
            *(i32x2*)(rowp + 32) = (i32x2){pack2(dd[8], dd[9]),   pack2(dd[10], dd[11])};
            *(i32x2*)(rowp + 48) = (i32x2){pack2(dd[12], dd[13]), pack2(dd[14], dd[15])};
        }
    };

    auto topo_gather = [&](int h, float (&tp)[16]) {
        const float* tb = topo + h * 625 + uc * 25 + hi * 4;
        #pragma unroll
        for (int r = 0; r < 16; r++) {
            int off = (r < 12) ? ((r & 3) + (r >> 2) * 8)
                    : (r == 12 ? (hi ? 0 : 24) : 0);   // pad offsets clamped in-bounds
            tp[r] = tb[off];
        }
    };

    // ---- this wave's single head-pair (r8 body) ----
    #pragma unroll
    for (int tsel = 0; tsel < 2; tsel++) {
        int nt = tsel ? (4 + hp) : hp;
        bf16x8 b0 = *(const bf16x8*)&wqk[(nt * 2 + 0) * 512 + lane * 8];
        bf16x8 b1 = *(const bf16x8*)&wqk[(nt * 2 + 1) * 512 + lane * 8];
        float bias = b_qk[(tsel ? 64 : 0) + hp * 16 + l15];
        unsigned short* buf = tsel ? kbuf : qbuf;
        #pragma unroll
        for (int mt = 0; mt < 2; mt++) {
            f32x4 d = MFMA16(yna[mt][0], b0, z4);
            d = MFMA16(yna[mt][1], b1, d);
            #pragma unroll
            for (int r = 0; r < 4; r++) {
                int u = mt * 16 + quad * 4 + r;
                if (u < 25) {
                    float val = d[r] + bias;
                    if (!tsel) val *= SCALE_L2E;
                    buf[u * 24 + l15] = bfh(val);
                }
            }
        }
    }

    float tp0[16];
    topo_gather(hp * 2, tp0);
    LGKM0();   // q/k visible

    f32x16 p0, p1;
    {
        bf16x8 ak = z8, bq = z8;
        if (hi == 0) {
            ak = *(const bf16x8*)&kbuf[r32 * 24 + 0];
            bq = *(const bf16x8*)&qbuf[r32 * 24 + 0];
        }
        p0 = __builtin_amdgcn_mfma_f32_32x32x16_bf16(ak, bq, z16, 0, 0, 0);
    }
    float tp1[16];
    topo_gather(hp * 2 + 1, tp1);
    {
        bf16x8 ak = z8, bq = z8;
        if (hi == 0) {
            ak = *(const bf16x8*)&kbuf[r32 * 24 + 8];
            bq = *(const bf16x8*)&qbuf[r32 * 24 + 8];
        }
        p1 = __builtin_amdgcn_mfma_f32_32x32x16_bf16(ak, bq, z16, 0, 0, 0);
    }
    softmax_store(p0, tp0, pb0);
    softmax_store(p1, tp1, pb1);

    // FW hh=0 (overlays q/k after dots reads; same-wave DS ordering)
    bf16x8 w2e[8];
    #pragma unroll
    for (int nt = 0; nt < 4; nt++) {
        int h = hp * 2;
        w2e[2 * nt]     = *(const bf16x8*)&w2f[((h * 4 + nt) * 2 + 0) * 512 + lane * 8];
        w2e[2 * nt + 1] = *(const bf16x8*)&w2f[((h * 4 + nt) * 2 + 1) * 512 + lane * 8];
    }
    #pragma unroll
    for (int nt = 0; nt < 4; nt++) {
        f32x4 dw0 = MFMA16(xa[0][0], w2e[2 * nt], z4);
        dw0 = MFMA16(xa[0][1], w2e[2 * nt + 1], dw0);
        f32x4 dw1 = MFMA16(xa[1][0], w2e[2 * nt], z4);
        dw1 = MFMA16(xa[1][1], w2e[2 * nt + 1], dw1);
        i32x2 q0 = {pack2(dw0[0], dw0[1]), pack2(dw0[2], dw0[3])};
        i32x2 q1 = {pack2(dw1[0], dw1[1]), pack2(dw1[2], dw1[3])};
        *(i32x2*)(w0p + nt * 1024 + l15 * 64) = q0;
        *(i32x2*)(w1p + nt * 1024 + l15 * 64) = q1;
    }
    bf16x8 w2o[8];
    #pragma unroll
    for (int nt = 0; nt < 4; nt++) {
        int h = hp * 2 + 1;
        w2o[2 * nt]     = *(const bf16x8*)&w2f[((h * 4 + nt) * 2 + 0) * 512 + lane * 8];
        w2o[2 * nt + 1] = *(const bf16x8*)&w2f[((h * 4 + nt) * 2 + 1) * 512 + lane * 8];
    }
    LGKM0();   // P0/P1 + FWT(hh=0) visible

    // PV hh=0
    {
        bf16x8 ag0 = *(const bf16x8*)(pb0 + l15 * 80 + quad * 16);
        bf16x8 ag1 = *(const bf16x8*)(pb0 + 1280 + l15 * 80 + quad * 16);
        #pragma unroll
        for (int nt = 0; nt < 4; nt++) {
            bf16x8 br = *(const bf16x8*)(brp + nt * 1024);
            acc[0][nt] = MFMA16(ag0, br, acc[0][nt]);
            acc[1][nt] = MFMA16(ag1, br, acc[1][nt]);
        }
    }

    // FW hh=1 -> FWT (after PV0 reads)
    #pragma unroll
    for (int nt = 0; nt < 4; nt++) {
        f32x4 dw0 = MFMA16(xa[0][0], w2o[2 * nt], z4);
        dw0 = MFMA16(xa[0][1], w2o[2 * nt + 1], dw0);
        f32x4 dw1 = MFMA16(xa[1][0], w2o[2 * nt], z4);
        dw1 = MFMA16(xa[1][1], w2o[2 * nt + 1], dw1);
        i32x2 q0 = {pack2(dw0[0], dw0[1]), pack2(dw0[2], dw0[3])};
        i32x2 q1 = {pack2(dw1[0], dw1[1]), pack2(dw1[2], dw1[3])};
        *(i32x2*)(w0p + nt * 1024 + l15 * 64) = q0;
        *(i32x2*)(w1p + nt * 1024 + l15 * 64) = q1;
    }
    LGKM0();   // FWT(hh=1) visible

    // PV hh=1
    {
        bf16x8 ag0 = *(const bf16x8*)(pb1 + l15 * 80 + quad * 16);
        bf16x8 ag1 = *(const bf16x8*)(pb1 + 1280 + l15 * 80 + quad * 16);
        #pragma unroll
        for (int nt = 0; nt < 4; nt++) {
            bf16x8 br = *(const bf16x8*)(brp + nt * 1024);
            acc[0][nt] = MFMA16(ag0, br, acc[0][nt]);
            acc[1][nt] = MFMA16(ag1, br, acc[1][nt]);
        }
    }

    // ---- cross-wave reduction: red[w][o][u] = 4 x 64 x 36 floats (36864 B) ----
    __syncthreads();                       // all wave-private LDS use done
    {
        float* red = (float*)smem + wv * 2304;
        #pragma unroll
        for (int mt = 0; mt < 2; mt++)
            #pragma unroll
            for (int nt = 0; nt < 4; nt++)
                *(f32x4*)&red[(nt * 16 + l15) * 36 + mt * 16 + quad * 4] = acc[mt][nt];
    }
    __syncthreads();

    // ---- epilogue: wave wv handles o in [wv*16, wv*16+16); residual from LDS ----
    {
        const float* redf = (const float*)smem;
        const int o = wv * 16 + l15;
        const float gA = bnA[o], gB = bnB[o];
        const float* xo = xrawF + o * 28;          // x residual from LDS (no 2nd HBM read)
        float* oo = og + (size_t)o * 6400;
        #pragma unroll
        for (int mt = 0; mt < 2; mt++) {
            const int ub = mt * 16 + quad * 4;
            f32x4 s = {0.f, 0.f, 0.f, 0.f};
            #pragma unroll
            for (int w = 0; w < 4; w++)
                s += *(const f32x4*)&redf[w * 2304 + o * 36 + ub];
            if (ub + 3 < 25) {
                f32x4 xr = *(const f32x4*)&xo[ub];
                f32x4 v;
                #pragma unroll
                for (int r = 0; r < 4; r++) v[r] = fmaxf(s[r] * gA + gB + xr[r], 0.f);
                *(f32x4*)&oo[ub] = v;
            } else if (ub < 25) {   // ub == 24
                oo[ub] = fmaxf(s[0] * gA + gB + xo[24], 0.f);
            }
        }
    }
}

extern "C" void kernel_launch(void* const* d_in, const int* in_sizes, int n_in,
                              void* d_out, int out_size, void* d_ws, size_t ws_size,
                              hipStream_t stream) {
    const float* x      = (const float*)d_in[0];
    const float* ln_g   = (const float*)d_in[1];
    const float* ln_b   = (const float*)d_in[2];
    const float* w_qk   = (const float*)d_in[3];
    const float* b_qk   = (const float*)d_in[4];
    const float* topo   = (const float*)d_in[5];
    const float* conv_w = (const float*)d_in[6];
    const float* conv_b = (const float*)d_in[7];
    const float* bn_g   = (const float*)d_in[8];
    const float* bn_b   = (const float*)d_in[9];
    const float* bn_m   = (const float*)d_in[10];
    const float* bn_v   = (const float*)d_in[11];
    float* outp = (float*)d_out;
    unsigned short* wsp = (unsigned short*)d_ws;

    hipLaunchKernelGGL(prep_kernel, dim3(161), dim3(256), 0, stream,
                       w_qk, conv_w, conv_b, bn_g, bn_b, bn_m, bn_v, wsp);
    hipLaunchKernelGGL(sagc_kernel, dim3(8192), dim3(256), 0, stream,
                       x, ln_g, ln_b, b_qk, topo, (const unsigned short*)wsp, outp);
}

// Round 10
// 183.544 us; speedup vs baseline: 1.5460x; 1.5460x over previous
//
#include <hip/hip_runtime.h>
#include <math.h>

#define SCALE_L2E 0.51006972157f   // (1/sqrt(8)) * log2(e) -- softmax done in exp2 domain
#define EPSV 1e-5f

typedef __attribute__((ext_vector_type(8))) short bf16x8;
typedef __attribute__((ext_vector_type(4))) float f32x4;
typedef __attribute__((ext_vector_type(16))) float f32x16;
typedef __attribute__((ext_vector_type(4))) int i32x4;
typedef __attribute__((ext_vector_type(2))) int i32x2;

static __device__ __forceinline__ unsigned short bfh(float f) {
    return (unsigned short)(__builtin_bit_cast(unsigned int, f) >> 16);
}
static __device__ __forceinline__ float bf2f(unsigned short s) {
    return __builtin_bit_cast(float, (unsigned int)s << 16);
}
static __device__ __forceinline__ int pack2(float lo, float hi) {
    return __builtin_amdgcn_perm(__builtin_bit_cast(unsigned int, hi),
                                 __builtin_bit_cast(unsigned int, lo), 0x07060302u);
}
#define LGKM0() __asm__ __volatile__("s_waitcnt lgkmcnt(0)" ::: "memory")

// ws layout: [0,8192) ushort wqk B-frags; [8192,40960) ushort W2ᵀ B-frags;
//            byte 81920: float bnA[64], bnB[64]
__global__ void prep_kernel(const float* __restrict__ w_qk,
                            const float* __restrict__ conv_w,
                            const float* __restrict__ conv_b,
                            const float* __restrict__ bn_g, const float* __restrict__ bn_b,
                            const float* __restrict__ bn_m, const float* __restrict__ bn_v,
                            unsigned short* __restrict__ ws) {
    int i = blockIdx.x * 256 + threadIdx.x;
    if (i < 8192) {
        // qk B-frag: frag(nt,ks): val = w_qk[k][n], k=ks*32+(l>>4)*8+j, n=nt*16+(l&15)
        int f = i >> 9, rem = i & 511, l = rem >> 3, j = rem & 7;
        int nt = f >> 1, ks = f & 1;
        int k = ks * 32 + (l >> 4) * 8 + j;
        int nn = nt * 16 + (l & 15);
        ws[i] = bfh(w_qk[k * 128 + nn]);
    } else if (i < 40960) {
        // W2ᵀ B-frag: frag(h,nt,ks): val = conv_w[h][o][c], c=ks*32+(l>>4)*8+j, o=nt*16+(l&15)
        int i2 = i - 8192;
        int g = i2 >> 9, rem = i2 & 511, l = rem >> 3, j = rem & 7;
        int h = g >> 3, nt = (g >> 1) & 3, ks = g & 1;
        int c = ks * 32 + (l >> 4) * 8 + j;
        int o = nt * 16 + (l & 15);
        ws[i] = bfh(conv_w[h * 4096 + o * 64 + c]);
    } else if (i < 41024) {
        int o = i - 40960;
        float gv = bn_g[o] * rsqrtf(bn_v[o] + EPSV);
        float bb = bn_b[o] - bn_m[o] * gv;
        float cb = 0.f;
        for (int h = 0; h < 8; h++) cb += conv_b[h * 64 + o];
        float* wsf = (float*)(ws + 40960);
        wsf[o] = gv;
        wsf[64 + o] = bb + cb * gv;
    }
}

// R10 = best kernel (r4 bench 185.9us, 98us dispatch, FETCH 57MB minimal)
// + XCD-CONTIGUOUS TILE MAPPING (T1, bijective; the ONLY never-varied axis).
// Rationale (MEASURED r0-r9): dur invariant 98+-2us across 5 structures while
// occupancy/chain/VALU/bytes all varied; effective BW pinned 1.2-1.5 TB/s
// (~20% of achievable) = DRAM short-burst inefficiency signature. x/out rows
// are 100B (not 64B-aligned) -> adjacent-t tiles SHARE cache lines; with
// tile=blockIdx round-robin across 8 XCDs, boundary lines are fetched by two
// L2s and output lines are PARTIALLY WRITTEN by two non-coherent L2s ->
// HBM-level partial-line RMW on every row boundary. Fix: bx in [0,2048):
//   tile_base = (bx&7)*1024 + (bx>>3)*4   (XCD k owns contiguous tiles
//   [1024k,1024(k+1)) = ~26MB contiguous x/out; blocks b,b+8 adjacent-t).
// 2048%8==0 -> bijective. Waves in a block cover t..t+3 (L1 merges boundaries).
// r9 lesson (MEASURED): runtime-indexed unpack -> VALU 94%, dur 204us. Keep
// frag builds compile-time-indexed (this base kernel already is).
// VGPR cap vs spill/occupancy (MEASURED r0-r4): cap 48 heavy spill | cap 64
// spill | cap 80/128 no spill; 80..128 same wave quantum. Do NOT tighten.
__global__ __launch_bounds__(256, 2)
void sagc_kernel(const float* __restrict__ x,
                 const float* __restrict__ ln_g, const float* __restrict__ ln_b,
                 const float* __restrict__ b_qk,
                 const float* __restrict__ topo,
                 const unsigned short* __restrict__ ws,
                 float* __restrict__ out)
{
    __shared__ __align__(16) unsigned char smem[32768];
    const int tid = threadIdx.x;
    const int lane = tid & 63, wv = tid >> 6;
    const int l15 = lane & 15, quad = lane >> 4;
    const int r32 = lane & 31, hi = lane >> 5;

    unsigned char* my = smem + wv * 8192;
    unsigned short* qbuf = (unsigned short*)my;            // [32][24] u16
    unsigned short* kbuf = (unsigned short*)(my + 1536);
    unsigned char*  fwb  = my;                             // FWT swizzled, 4096 B
    unsigned char*  ghb  = my + 4096;                      // Gh swizzled, 2 x 2048 B

    const unsigned short* wqk = ws;
    const unsigned short* w2f = ws + 8192;
    const float* bnA = (const float*)(ws + 40960);
    const float* bnB = bnA + 64;

    // XCD-contiguous bijective mapping: XCD (bx&7) owns tiles [1024*(bx&7), +1024)
    const int bx = blockIdx.x;
    const int tile = (bx & 7) * 1024 + ((bx >> 3) << 2) + wv;
    const int n = tile >> 8, t = tile & 255;
    const float* xg = x + (size_t)n * 409600 + (size_t)t * 25;   // + c*6400 + v
    float* og = out + (size_t)n * 409600 + (size_t)t * 25;

    // ---- direct-register x load (no LDS staging): xf[mt][ks][j] = x[c][v], 0 at v>=25 ----
    float xf[2][2][8];
    #pragma unroll
    for (int mt = 0; mt < 2; mt++) {
        const int v = mt * 16 + l15;
        const bool ok = (v < 25);
        const float* xc = xg + v;
        #pragma unroll
        for (int ks = 0; ks < 2; ks++)
            #pragma unroll
            for (int j = 0; j < 8; j++) {
                int c = ks * 32 + quad * 8 + j;
                xf[mt][ks][j] = ok ? xc[c * 6400] : 0.f;
            }
    }

    // ---- pack x A-frags; accumulate per-row sums for LN stats ----
    bf16x8 xa[2][2];
    float sum_[2] = {0.f, 0.f}, ssq_[2] = {0.f, 0.f};
    #pragma unroll
    for (int mt = 0; mt < 2; mt++)
        #pragma unroll
        for (int ks = 0; ks < 2; ks++) {
            i32x4 pa;
            #pragma unroll
            for (int q = 0; q < 4; q++)
                pa[q] = pack2(xf[mt][ks][2 * q], xf[mt][ks][2 * q + 1]);
            xa[mt][ks] = __builtin_bit_cast(bf16x8, pa);
            #pragma unroll
            for (int j = 0; j < 8; j++) {
                float a = xf[mt][ks][j];
                sum_[mt] += a;
                ssq_[mt] += a * a;
            }
        }

    // ---- LN stats via cross-quad shuffle reduce (lanes l15, +16, +32, +48) ----
    float muv[2], rsv[2];
    #pragma unroll
    for (int mt = 0; mt < 2; mt++) {
        sum_[mt] += __shfl_xor(sum_[mt], 16);
        sum_[mt] += __shfl_xor(sum_[mt], 32);
        ssq_[mt] += __shfl_xor(ssq_[mt], 16);
        ssq_[mt] += __shfl_xor(ssq_[mt], 32);
        muv[mt] = sum_[mt] * 0.015625f;
        rsv[mt] = rsqrtf(ssq_[mt] * 0.015625f - muv[mt] * muv[mt] + EPSV);
    }

    // ---- normalize in-register -> yn A-frags ----
    bf16x8 yna[2][2];
    #pragma unroll
    for (int ks = 0; ks < 2; ks++) {
        f32x4 ga = *(const f32x4*)&ln_g[ks * 32 + quad * 8];
        f32x4 gb = *(const f32x4*)&ln_g[ks * 32 + quad * 8 + 4];
        f32x4 ba = *(const f32x4*)&ln_b[ks * 32 + quad * 8];
        f32x4 bb = *(const f32x4*)&ln_b[ks * 32 + quad * 8 + 4];
        #pragma unroll
        for (int mt = 0; mt < 2; mt++) {
            float yv[8];
            #pragma unroll
            for (int j = 0; j < 8; j++) {
                float g = (j < 4) ? ga[j] : gb[j - 4];
                float bt = (j < 4) ? ba[j] : bb[j - 4];
                yv[j] = (xf[mt][ks][j] - muv[mt]) * rsv[mt] * g + bt;
            }
            i32x4 p;
            #pragma unroll
            for (int q = 0; q < 4; q++) p[q] = pack2(yv[2 * q], yv[2 * q + 1]);
            yna[mt][ks] = __builtin_bit_cast(bf16x8, p);
        }
    }

    // ---- accumulators ----
    f32x4 acc[2][4];
    #pragma unroll
    for (int mt = 0; mt < 2; mt++)
        #pragma unroll
        for (int nt = 0; nt < 4; nt++)
            acc[mt][nt] = (f32x4){0.f, 0.f, 0.f, 0.f};

    const f32x4 z4 = {0.f, 0.f, 0.f, 0.f};
    const bf16x8 z8 = {0, 0, 0, 0, 0, 0, 0, 0};

    // per-lane swizzled-address constants (loop-invariant)
    const int sw4 = (l15 >> 2) & 3;
    const int blkA = ((r32 >> 3) ^ hi) << 4;
    unsigned char* gwA = ghb + hi * 256 + (r32 & 7) * 2 + blkA;         // dots write, (r>>2)&1==0
    unsigned char* gwB = ghb + hi * 256 + (r32 & 7) * 2 + (blkA ^ 32);  // dots write, (r>>2)&1==1
    unsigned char* w0p = fwb + ((((quad >> 1) ^ sw4)) << 4) + (quad & 1) * 8;       // FW cols quad*4
    unsigned char* w1p = fwb + (((((quad >> 1) ^ sw4)) ^ 2) << 4) + (quad & 1) * 8; // FW cols 16+quad*4
    unsigned char* brp = fwb + l15 * 64 + ((quad ^ sw4) << 4);                      // FW B-frag read

    // ---- head-pair loop (fully unrolled; global prefetches placed to hide latency) ----
    #pragma unroll
    for (int hp = 0; hp < 4; hp++) {
        // qk tiles: q-tile nt=hp (SCALE*log2e folded), k-tile nt=4+hp
        #pragma unroll
        for (int tsel = 0; tsel < 2; tsel++) {
            int nt = tsel ? (4 + hp) : hp;
            bf16x8 b0 = *(const bf16x8*)&wqk[(nt * 2 + 0) * 512 + lane * 8];
            bf16x8 b1 = *(const bf16x8*)&wqk[(nt * 2 + 1) * 512 + lane * 8];
            float bias = b_qk[(tsel ? 64 : 0) + hp * 16 + l15];
            unsigned short* buf = tsel ? kbuf : qbuf;
            #pragma unroll
            for (int mt = 0; mt < 2; mt++) {
                f32x4 d = __builtin_amdgcn_mfma_f32_16x16x32_bf16(yna[mt][0], b0, z4, 0, 0, 0);
                d = __builtin_amdgcn_mfma_f32_16x16x32_bf16(yna[mt][1], b1, d, 0, 0, 0);
                #pragma unroll
                for (int r = 0; r < 4; r++) {
                    int u = mt * 16 + quad * 4 + r;
                    if (u < 25) {
                        float val = d[r] + bias;
                        if (!tsel) val *= SCALE_L2E;
                        buf[u * 24 + l15] = bfh(val);
                    }
                }
            }
        }
        LGKM0();

        // dots: per head one 32x32x16 MFMA (K=8 real + 8 zero); swizzled Gh writes
        #pragma unroll
        for (int hh = 0; hh < 2; hh++) {
            bf16x8 aq = z8, bk = z8;
            if (hi == 0) {
                aq = *(const bf16x8*)&qbuf[r32 * 24 + hh * 8];
                bk = *(const bf16x8*)&kbuf[r32 * 24 + hh * 8];
            }
            f32x16 dd = {0.f,0.f,0.f,0.f,0.f,0.f,0.f,0.f,0.f,0.f,0.f,0.f,0.f,0.f,0.f,0.f};
            dd = __builtin_amdgcn_mfma_f32_32x32x16_bf16(aq, bk, dd, 0, 0, 0);
            #pragma unroll
            for (int r = 0; r < 16; r++) {
                int ub = (r & 3) + 8 * (r >> 2);
                if (ub + 4 * hi < 25) {
                    unsigned char* p = (((r >> 2) & 1) ? gwB : gwA) + hh * 2048 + ub * 64;
                    *(unsigned short*)p = bfh(dd[r]);
                }
            }
        }

        // prefetch this hp's topo row NOW (vmcnt load; latency hides under the
        // lgkm wait + softmax unpack VALU)
        float tpv[25];
        {
            const float* tp = topo + (hp * 2 + hi) * 625 + (r32 < 25 ? r32 : 0) * 25;
            #pragma unroll
            for (int v = 0; v < 25; v++) tpv[v] = tp[v];
        }
        LGKM0();

        // softmax * topo (50 active lanes: 2 heads x 25 rows), in-place, pad cols zeroed
        {
            int smh = hi, su = r32;
            if (su < 25) {
                unsigned char* rowb = ghb + smh * 2048 + su * 64;
                int sz = ((su >> 2) & 3) << 4;
                i32x4 ra = *(const i32x4*)(rowb + (sz ^ 0));
                i32x4 rb = *(const i32x4*)(rowb + (sz ^ 16));
                i32x4 rc = *(const i32x4*)(rowb + (sz ^ 32));
                float f[25];
                #pragma unroll
                for (int w = 0; w < 4; w++) {
                    f[2 * w]      = __builtin_bit_cast(float, (unsigned)ra[w] << 16);
                    f[2 * w + 1]  = __builtin_bit_cast(float, (unsigned)ra[w] & 0xFFFF0000u);
                    f[8 + 2 * w]  = __builtin_bit_cast(float, (unsigned)rb[w] << 16);
                    f[9 + 2 * w]  = __builtin_bit_cast(float, (unsigned)rb[w] & 0xFFFF0000u);
                    f[16 + 2 * w] = __builtin_bit_cast(float, (unsigned)rc[w] << 16);
                    f[17 + 2 * w] = __builtin_bit_cast(float, (unsigned)rc[w] & 0xFFFF0000u);
                }
                f[24] = bf2f(*(const unsigned short*)(rowb + (sz ^ 48)));
                // tree max
                float g12[12];
                #pragma unroll
                for (int i2 = 0; i2 < 12; i2++) g12[i2] = fmaxf(f[i2], f[i2 + 12]);
                #pragma unroll
                for (int i2 = 0; i2 < 6; i2++) g12[i2] = fmaxf(g12[i2], g12[i2 + 6]);
                float m = fmaxf(fmaxf(fmaxf(g12[0], g12[1]), fmaxf(g12[2], g12[3])),
                                fmaxf(fmaxf(g12[4], g12[5]), f[24]));
                // exp2 (log2e pre-folded into q) + 4-way sum
                float s0 = 0.f, s1 = 0.f, s2 = 0.f, s3 = 0.f;
                #pragma unroll
                for (int v = 0; v < 24; v += 4) {
                    f[v]     = __builtin_amdgcn_exp2f(f[v] - m);     s0 += f[v];
                    f[v + 1] = __builtin_amdgcn_exp2f(f[v + 1] - m); s1 += f[v + 1];
                    f[v + 2] = __builtin_amdgcn_exp2f(f[v + 2] - m); s2 += f[v + 2];
                    f[v + 3] = __builtin_amdgcn_exp2f(f[v + 3] - m); s3 += f[v + 3];
                }
                f[24] = __builtin_amdgcn_exp2f(f[24] - m);
                float inv = __builtin_amdgcn_rcpf(((s0 + s1) + (s2 + s3)) + f[24]);
                #pragma unroll
                for (int v = 0; v < 25; v++) f[v] = f[v] * inv * tpv[v];
                int d[12];
                #pragma unroll
                for (int p = 0; p < 12; p++) d[p] = pack2(f[2 * p], f[2 * p + 1]);
                *(i32x4*)(rowb + (sz ^ 0))  = (i32x4){d[0], d[1], d[2], d[3]};
                *(i32x4*)(rowb + (sz ^ 16)) = (i32x4){d[4], d[5], d[6], d[7]};
                *(i32x4*)(rowb + (sz ^ 32)) = (i32x4){d[8], d[9], d[10], d[11]};
                *(i32x4*)(rowb + (sz ^ 48)) = (i32x4){pack2(f[24], 0.f), 0, 0, 0};
            }
        }

        // early-issue W2^T frags for hh=0 (vmcnt; hides under the wait below)
        bf16x8 w2e[8];
        #pragma unroll
        for (int nt = 0; nt < 4; nt++) {
            int h = hp * 2;
            w2e[2 * nt]     = *(const bf16x8*)&w2f[((h * 4 + nt) * 2 + 0) * 512 + lane * 8];
            w2e[2 * nt + 1] = *(const bf16x8*)&w2f[((h * 4 + nt) * 2 + 1) * 512 + lane * 8];
        }
        LGKM0();

        // ---- FW hh=0: FW = feat @ W2ᵀ (w2e pre-issued) -> FWT swizzled ----
        #pragma unroll
        for (int nt = 0; nt < 4; nt++) {
            f32x4 dw0 = __builtin_amdgcn_mfma_f32_16x16x32_bf16(xa[0][0], w2e[2 * nt], z4, 0, 0, 0);
            dw0 = __builtin_amdgcn_mfma_f32_16x16x32_bf16(xa[0][1], w2e[2 * nt + 1], dw0, 0, 0, 0);
            f32x4 dw1 = __builtin_amdgcn_mfma_f32_16x16x32_bf16(xa[1][0], w2e[2 * nt], z4, 0, 0, 0);
            dw1 = __builtin_amdgcn_mfma_f32_16x16x32_bf16(xa[1][1], w2e[2 * nt + 1], dw1, 0, 0, 0);
            i32x2 q0 = {pack2(dw0[0], dw0[1]), pack2(dw0[2], dw0[3])};
            i32x2 q1 = {pack2(dw1[0], dw1[1]), pack2(dw1[2], dw1[3])};
            *(i32x2*)(w0p + nt * 1024 + l15 * 64) = q0;
            *(i32x2*)(w1p + nt * 1024 + l15 * 64) = q1;
        }
        // early-issue W2^T frags for hh=1 (hides under hh=0's wait + PV)
        bf16x8 w2o[8];
        #pragma unroll
        for (int nt = 0; nt < 4; nt++) {
            int h = hp * 2 + 1;
            w2o[2 * nt]     = *(const bf16x8*)&w2f[((h * 4 + nt) * 2 + 0) * 512 + lane * 8];
            w2o[2 * nt + 1] = *(const bf16x8*)&w2f[((h * 4 + nt) * 2 + 1) * 512 + lane * 8];
        }
        LGKM0();

        // ---- PV hh=0: acc += G_0 @ FW_0 ----
        {
            unsigned char* agp = ghb + l15 * 64 + ((quad ^ sw4) << 4);
            bf16x8 ag0 = *(const bf16x8*)agp;
            bf16x8 ag1 = *(const bf16x8*)(agp + 1024);
            #pragma unroll
            for (int nt = 0; nt < 4; nt++) {
                bf16x8 br = *(const bf16x8*)(brp + nt * 1024);
                acc[0][nt] = __builtin_amdgcn_mfma_f32_16x16x32_bf16(ag0, br, acc[0][nt], 0, 0, 0);
                acc[1][nt] = __builtin_amdgcn_mfma_f32_16x16x32_bf16(ag1, br, acc[1][nt], 0, 0, 0);
            }
        }

        // ---- FW hh=1 -> FWT (same-wave DS ordering keeps this after PV0's reads) ----
        #pragma unroll
        for (int nt = 0; nt < 4; nt++) {
            f32x4 dw0 = __builtin_amdgcn_mfma_f32_16x16x32_bf16(xa[0][0], w2o[2 * nt], z4, 0, 0, 0);
            dw0 = __builtin_amdgcn_mfma_f32_16x16x32_bf16(xa[0][1], w2o[2 * nt + 1], dw0, 0, 0, 0);
            f32x4 dw1 = __builtin_amdgcn_mfma_f32_16x16x32_bf16(xa[1][0], w2o[2 * nt], z4, 0, 0, 0);
            dw1 = __builtin_amdgcn_mfma_f32_16x16x32_bf16(xa[1][1], w2o[2 * nt + 1], dw1, 0, 0, 0);
            i32x2 q0 = {pack2(dw0[0], dw0[1]), pack2(dw0[2], dw0[3])};
            i32x2 q1 = {pack2(dw1[0], dw1[1]), pack2(dw1[2], dw1[3])};
            *(i32x2*)(w0p + nt * 1024 + l15 * 64) = q0;
            *(i32x2*)(w1p + nt * 1024 + l15 * 64) = q1;
        }
        LGKM0();

        // ---- PV hh=1: acc += G_1 @ FW_1 ----
        {
            unsigned char* agp = ghb + 2048 + l15 * 64 + ((quad ^ sw4) << 4);
            bf16x8 ag0 = *(const bf16x8*)agp;
            bf16x8 ag1 = *(const bf16x8*)(agp + 1024);
            #pragma unroll
            for (int nt = 0; nt < 4; nt++) {
                bf16x8 br = *(const bf16x8*)(brp + nt * 1024);
                acc[0][nt] = __builtin_amdgcn_mfma_f32_16x16x32_bf16(ag0, br, acc[0][nt], 0, 0, 0);
                acc[1][nt] = __builtin_amdgcn_mfma_f32_16x16x32_bf16(ag1, br, acc[1][nt], 0, 0, 0);
            }
        }
    }

    // ---- epilogue: BN + residual + ReLU, direct global store ----
    #pragma unroll
    for (int nt = 0; nt < 4; nt++) {
        int o = nt * 16 + l15;
        float gA = bnA[o], gB = bnB[o];
        #pragma unroll
        for (int mt = 0; mt < 2; mt++) {
            int ub = mt * 16 + quad * 4;
            #pragma unroll
            for (int r = 0; r < 4; r++) {
                int u = ub + r;
                if (u < 25) {
                    float val = acc[mt][nt][r] * gA + gB + xg[o * 6400 + u];
                    og[o * 6400 + u] = fmaxf(val, 0.f);
                }
            }
        }
    }
}

extern "C" void kernel_launch(void* const* d_in, const int* in_sizes, int n_in,
                              void* d_out, int out_size, void* d_ws, size_t ws_size,
                              hipStream_t stream) {
    const float* x      = (const float*)d_in[0];
    const float* ln_g   = (const float*)d_in[1];
    const float* ln_b   = (const float*)d_in[2];
    const float* w_qk   = (const float*)d_in[3];
    const float* b_qk   = (const float*)d_in[4];
    const float* topo   = (const float*)d_in[5];
    const float* conv_w = (const float*)d_in[6];
    const float* conv_b = (const float*)d_in[7];
    const float* bn_g   = (const float*)d_in[8];
    const float* bn_b   = (const float*)d_in[9];
    const float* bn_m   = (const float*)d_in[10];
    const float* bn_v   = (const float*)d_in[11];
    float* outp = (float*)d_out;
    unsigned short* wsp = (unsigned short*)d_ws;

    hipLaunchKernelGGL(prep_kernel, dim3(161), dim3(256), 0, stream,
                       w_qk, conv_w, conv_b, bn_g, bn_b, bn_m, bn_v, wsp);
    hipLaunchKernelGGL(sagc_kernel, dim3(2048), dim3(256), 0, stream,
                       x, ln_g, ln_b, b_qk, topo, (const unsigned short*)wsp, outp);
}

// Round 11
// 180.818 us; speedup vs baseline: 1.5693x; 1.0151x over previous
//
#include <hip/hip_runtime.h>
#include <math.h>

#define SCALE_L2E 0.51006972157f   // (1/sqrt(8)) * log2(e) -- softmax done in exp2 domain
#define EPSV 1e-5f

typedef __attribute__((ext_vector_type(8))) short bf16x8;
typedef __attribute__((ext_vector_type(4))) float f32x4;
typedef __attribute__((ext_vector_type(16))) float f32x16;
typedef __attribute__((ext_vector_type(4))) int i32x4;
typedef __attribute__((ext_vector_type(2))) int i32x2;

static __device__ __forceinline__ unsigned short bfh(float f) {
    return (unsigned short)(__builtin_bit_cast(unsigned int, f) >> 16);
}
static __device__ __forceinline__ int pack2(float lo, float hi) {
    return __builtin_amdgcn_perm(__builtin_bit_cast(unsigned int, hi),
                                 __builtin_bit_cast(unsigned int, lo), 0x07060302u);
}
#define LGKM0() __asm__ __volatile__("s_waitcnt lgkmcnt(0)" ::: "memory")

// ws layout: [0,8192) ushort wqk B-frags; [8192,40960) ushort W2ᵀ B-frags;
//            byte 81920: float bnA[64], bnB[64]
__global__ void prep_kernel(const float* __restrict__ w_qk,
                            const float* __restrict__ conv_w,
                            const float* __restrict__ conv_b,
                            const float* __restrict__ bn_g, const float* __restrict__ bn_b,
                            const float* __restrict__ bn_m, const float* __restrict__ bn_v,
                            unsigned short* __restrict__ ws) {
    int i = blockIdx.x * 256 + threadIdx.x;
    if (i < 8192) {
        // qk B-frag: frag(nt,ks): val = w_qk[k][n], k=ks*32+(l>>4)*8+j, n=nt*16+(l&15)
        int f = i >> 9, rem = i & 511, l = rem >> 3, j = rem & 7;
        int nt = f >> 1, ks = f & 1;
        int k = ks * 32 + (l >> 4) * 8 + j;
        int nn = nt * 16 + (l & 15);
        ws[i] = bfh(w_qk[k * 128 + nn]);
    } else if (i < 40960) {
        // W2ᵀ B-frag: frag(h,nt,ks): val = conv_w[h][o][c], c=ks*32+(l>>4)*8+j, o=nt*16+(l&15)
        int i2 = i - 8192;
        int g = i2 >> 9, rem = i2 & 511, l = rem >> 3, j = rem & 7;
        int h = g >> 3, nt = (g >> 1) & 3, ks = g & 1;
        int c = ks * 32 + (l >> 4) * 8 + j;
        int o = nt * 16 + (l & 15);
        ws[i] = bfh(conv_w[h * 4096 + o * 64 + c]);
    } else if (i < 41024) {
        int o = i - 40960;
        float gv = bn_g[o] * rsqrtf(bn_v[o] + EPSV);
        float bb = bn_b[o] - bn_m[o] * gv;
        float cb = 0.f;
        for (int h = 0; h < 8; h++) cb += conv_b[h * 64 + o];
        float* wsf = (float*)(ws + 40960);
        wsf[o] = gv;
        wsf[64 + o] = bb + cb * gv;
    }
}

// R11 = r5 (swapped-dots, in-register softmax, 3 lgkm waits/hp; verified r5
// bench 188.8 / dispatch 98.5, FETCH 42.5) + r10's XCD-CONTIGUOUS MAPPING
// (verified: r4->r10 = 98->91us, FETCH 57->36.5, WRITE 60->52; partial-line
// cross-XCD RMW on 100B rows eliminated). Pure composition of two verified
// kernels. One change vs r5: dots->softmax SERIALIZED per head (r5 computed
// p0,p1 before either softmax -> 88 VGPR -> occupancy dropped to 20.5%;
// serializing cuts peak live regs to land back at the 80-VGPR/2.25-wave tier).
// Floor model (MEASURED r4/r5/r7/r8/r10): dur ~= VALU_work/VALUBusy
// (26.4us/0.29 = 91us at r10). This round targets VALU_work (no Gh LDS
// round-trip, no 50-op unpack) and wait count (3 vs 5 per hp).
// VGPR cap vs spill (MEASURED): cap 48/64 spill; 80..128 same wave quantum.
// Spill tripwire: FETCH > 60 MB => revert. PRE-COMMIT: dur >= 88us =>
// structural floor confirmed; declare ROOFLINE next round.
__global__ __launch_bounds__(256, 2)
void sagc_kernel(const float* __restrict__ x,
                 const float* __restrict__ ln_g, const float* __restrict__ ln_b,
                 const float* __restrict__ b_qk,
                 const float* __restrict__ topo,
                 const unsigned short* __restrict__ ws,
                 float* __restrict__ out)
{
    __shared__ __align__(16) unsigned char smem[36864];
    const int tid = threadIdx.x;
    const int lane = tid & 63, wv = tid >> 6;
    const int l15 = lane & 15, quad = lane >> 4;
    const int r32 = lane & 31, hi = lane >> 5;

    unsigned char* my = smem + wv * 9216;
    unsigned short* qbuf = (unsigned short*)my;            // [32][24] u16
    unsigned short* kbuf = (unsigned short*)(my + 1536);
    unsigned char*  fwb  = my;                             // FWT swizzled (overlays q/k)
    unsigned char*  pb0  = my + 4096;                      // P0 [32][40] u16
    unsigned char*  pb1  = my + 4096 + 2560;               // P1

    const unsigned short* wqk = ws;
    const unsigned short* w2f = ws + 8192;
    const float* bnA = (const float*)(ws + 40960);
    const float* bnB = bnA + 64;

    // XCD-contiguous bijective mapping (r10, MEASURED -7%): XCD (bx&7) owns
    // tiles [1024*(bx&7), +1024); blocks b,b+8 adjacent-t on the same XCD.
    const int bx = blockIdx.x;
    const int tile = (bx & 7) * 1024 + ((bx >> 3) << 2) + wv;
    const int n = tile >> 8, t = tile & 255;
    const float* xg = x + (size_t)n * 409600 + (size_t)t * 25;   // + c*6400 + v
    float* og = out + (size_t)n * 409600 + (size_t)t * 25;

    // ---- direct-register x load: xf[mt][ks][j] = x[c][v], 0 at v>=25 ----
    float xf[2][2][8];
    #pragma unroll
    for (int mt = 0; mt < 2; mt++) {
        const int v = mt * 16 + l15;
        const bool ok = (v < 25);
        const float* xc = xg + v;
        #pragma unroll
        for (int ks = 0; ks < 2; ks++)
            #pragma unroll
            for (int j = 0; j < 8; j++) {
                int c = ks * 32 + quad * 8 + j;
                xf[mt][ks][j] = ok ? xc[c * 6400] : 0.f;
            }
    }

    // ---- pack x A-frags; per-row sums for LN stats ----
    bf16x8 xa[2][2];
    float sum_[2] = {0.f, 0.f}, ssq_[2] = {0.f, 0.f};
    #pragma unroll
    for (int mt = 0; mt < 2; mt++)
        #pragma unroll
        for (int ks = 0; ks < 2; ks++) {
            i32x4 pa;
            #pragma unroll
            for (int q = 0; q < 4; q++)
                pa[q] = pack2(xf[mt][ks][2 * q], xf[mt][ks][2 * q + 1]);
            xa[mt][ks] = __builtin_bit_cast(bf16x8, pa);
            #pragma unroll
            for (int j = 0; j < 8; j++) {
                float a = xf[mt][ks][j];
                sum_[mt] += a;
                ssq_[mt] += a * a;
            }
        }

    // ---- LN stats via cross-quad shuffle reduce ----
    float muv[2], rsv[2];
    #pragma unroll
    for (int mt = 0; mt < 2; mt++) {
        sum_[mt] += __shfl_xor(sum_[mt], 16);
        sum_[mt] += __shfl_xor(sum_[mt], 32);
        ssq_[mt] += __shfl_xor(ssq_[mt], 16);
        ssq_[mt] += __shfl_xor(ssq_[mt], 32);
        muv[mt] = sum_[mt] * 0.015625f;
        rsv[mt] = rsqrtf(ssq_[mt] * 0.015625f - muv[mt] * muv[mt] + EPSV);
    }

    // ---- normalize in-register -> yn A-frags ----
    bf16x8 yna[2][2];
    #pragma unroll
    for (int ks = 0; ks < 2; ks++) {
        f32x4 ga = *(const f32x4*)&ln_g[ks * 32 + quad * 8];
        f32x4 gb = *(const f32x4*)&ln_g[ks * 32 + quad * 8 + 4];
        f32x4 ba = *(const f32x4*)&ln_b[ks * 32 + quad * 8];
        f32x4 bb = *(const f32x4*)&ln_b[ks * 32 + quad * 8 + 4];
        #pragma unroll
        for (int mt = 0; mt < 2; mt++) {
            float yv[8];
            #pragma unroll
            for (int j = 0; j < 8; j++) {
                float g = (j < 4) ? ga[j] : gb[j - 4];
                float bt = (j < 4) ? ba[j] : bb[j - 4];
                yv[j] = (xf[mt][ks][j] - muv[mt]) * rsv[mt] * g + bt;
            }
            i32x4 p;
            #pragma unroll
            for (int q = 0; q < 4; q++) p[q] = pack2(yv[2 * q], yv[2 * q + 1]);
            yna[mt][ks] = __builtin_bit_cast(bf16x8, p);
        }
    }

    // ---- accumulators ----
    f32x4 acc[2][4];
    #pragma unroll
    for (int mt = 0; mt < 2; mt++)
        #pragma unroll
        for (int nt = 0; nt < 4; nt++)
            acc[mt][nt] = (f32x4){0.f, 0.f, 0.f, 0.f};

    const f32x4 z4 = {0.f, 0.f, 0.f, 0.f};
    const bf16x8 z8 = {0, 0, 0, 0, 0, 0, 0, 0};
    const f32x16 z16 = {0.f,0.f,0.f,0.f,0.f,0.f,0.f,0.f,0.f,0.f,0.f,0.f,0.f,0.f,0.f,0.f};

    // FWT swizzle constants (16B block ^= (l15>>2)&3)
    const int sw4 = (l15 >> 2) & 3;
    unsigned char* w0p = fwb + ((((quad >> 1) ^ sw4)) << 4) + (quad & 1) * 8;
    unsigned char* w1p = fwb + (((((quad >> 1) ^ sw4)) ^ 2) << 4) + (quad & 1) * 8;
    unsigned char* brp = fwb + l15 * 64 + ((quad ^ sw4) << 4);

    const int uc = (r32 < 25) ? r32 : 24;   // clamped topo row

    // in-register softmax + P store (verified r5 layout). dd: lane r32 = row u;
    // v(r) = (r&3)+8*(r>>2)+4*hi.
    auto softmax_store = [&](f32x16& dd, const float* tp, unsigned char* Pb) {
        dd[12] = hi ? -3e30f : dd[12];
        dd[13] = -3e30f; dd[14] = -3e30f; dd[15] = -3e30f;
        float t8[8];
        #pragma unroll
        for (int r = 0; r < 8; r++) t8[r] = fmaxf(dd[r], dd[r + 8]);
        #pragma unroll
        for (int r = 0; r < 4; r++) t8[r] = fmaxf(t8[r], t8[r + 4]);
        float m = fmaxf(fmaxf(t8[0], t8[1]), fmaxf(t8[2], t8[3]));
        m = fmaxf(m, __shfl_xor(m, 32));
        float s0 = 0.f, s1 = 0.f, s2 = 0.f, s3 = 0.f;
        #pragma unroll
        for (int r = 0; r < 16; r += 4) {
            dd[r]     = __builtin_amdgcn_exp2f(dd[r] - m);     s0 += dd[r];
            dd[r + 1] = __builtin_amdgcn_exp2f(dd[r + 1] - m); s1 += dd[r + 1];
            dd[r + 2] = __builtin_amdgcn_exp2f(dd[r + 2] - m); s2 += dd[r + 2];
            dd[r + 3] = __builtin_amdgcn_exp2f(dd[r + 3] - m); s3 += dd[r + 3];
        }
        float s = (s0 + s1) + (s2 + s3);
        s += __shfl_xor(s, 32);
        float inv = __builtin_amdgcn_rcpf(s);
        #pragma unroll
        for (int r = 0; r < 16; r++) dd[r] = dd[r] * inv * tp[r];
        if (r32 < 25) {
            unsigned char* rowp = Pb + r32 * 80 + hi * 8;
            *(i32x2*)(rowp +  0) = (i32x2){pack2(dd[0], dd[1]),   pack2(dd[2], dd[3])};
            *(i32x2*)(rowp + 16) = (i32x2){pack2(dd[4], dd[5]),   pack2(dd[6], dd[7])};
            *(i32x2*)(rowp + 32) = (i32x2){pack2(dd[8], dd[9]),   pack2(dd[10], dd[11])};
            *(i32x2*)(rowp + 48) = (i32x2){pack2(dd[12], dd[13]), pack2(dd[14], dd[15])};
        }
    };

    auto topo_gather = [&](int h, float (&tp)[16]) {
        const float* tb = topo + h * 625 + uc * 25 + hi * 4;
        #pragma unroll
        for (int r = 0; r < 16; r++) {
            int off = (r < 12) ? ((r & 3) + (r >> 2) * 8)
                    : (r == 12 ? (hi ? 0 : 24) : 0);   // pad offsets clamped in-bounds
            tp[r] = tb[off];
        }
    };

    // ---- head-pair loop ----
    #pragma unroll
    for (int hp = 0; hp < 4; hp++) {
        // qk tiles: q-tile nt=hp (SCALE*log2e folded), k-tile nt=4+hp
        #pragma unroll
        for (int tsel = 0; tsel < 2; tsel++) {
            int nt = tsel ? (4 + hp) : hp;
            bf16x8 b0 = *(const bf16x8*)&wqk[(nt * 2 + 0) * 512 + lane * 8];
            bf16x8 b1 = *(const bf16x8*)&wqk[(nt * 2 + 1) * 512 + lane * 8];
            float bias = b_qk[(tsel ? 64 : 0) + hp * 16 + l15];
            unsigned short* buf = tsel ? kbuf : qbuf;
            #pragma unroll
            for (int mt = 0; mt < 2; mt++) {
                f32x4 d = __builtin_amdgcn_mfma_f32_16x16x32_bf16(yna[mt][0], b0, z4, 0, 0, 0);
                d = __builtin_amdgcn_mfma_f32_16x16x32_bf16(yna[mt][1], b1, d, 0, 0, 0);
                #pragma unroll
                for (int r = 0; r < 4; r++) {
                    int u = mt * 16 + quad * 4 + r;
                    if (u < 25) {
                        float val = d[r] + bias;
                        if (!tsel) val *= SCALE_L2E;
                        buf[u * 24 + l15] = bfh(val);
                    }
                }
            }
        }

        // topo gather hh=0 (vmcnt loads; in flight across the wait)
        float tp0[16];
        topo_gather(hp * 2, tp0);
        LGKM0();   // q/k visible

        // dots hh=0 SWAPPED (A=K, B=Q) -> softmax0 (serialized: cuts peak regs)
        {
            f32x16 p0;
            bf16x8 ak = z8, bq = z8;
            if (hi == 0) {
                ak = *(const bf16x8*)&kbuf[r32 * 24 + 0];
                bq = *(const bf16x8*)&qbuf[r32 * 24 + 0];
            }
            p0 = __builtin_amdgcn_mfma_f32_32x32x16_bf16(ak, bq, z16, 0, 0, 0);
            softmax_store(p0, tp0, pb0);
        }
        // dots hh=1 -> softmax1
        {
            float tp1[16];
            topo_gather(hp * 2 + 1, tp1);
            f32x16 p1;
            bf16x8 ak = z8, bq = z8;
            if (hi == 0) {
                ak = *(const bf16x8*)&kbuf[r32 * 24 + 8];
                bq = *(const bf16x8*)&qbuf[r32 * 24 + 8];
            }
            p1 = __builtin_amdgcn_mfma_f32_32x32x16_bf16(ak, bq, z16, 0, 0, 0);
            softmax_store(p1, tp1, pb1);
        }

        // W2^T frags hh=0 (vmcnt; L2-hot)
        bf16x8 w2e[8];
        #pragma unroll
        for (int nt = 0; nt < 4; nt++) {
            int h = hp * 2;
            w2e[2 * nt]     = *(const bf16x8*)&w2f[((h * 4 + nt) * 2 + 0) * 512 + lane * 8];
            w2e[2 * nt + 1] = *(const bf16x8*)&w2f[((h * 4 + nt) * 2 + 1) * 512 + lane * 8];
        }

        // FW hh=0 (FWT overlays q/k region; same-wave DS order keeps it after dots reads)
        #pragma unroll
        for (int nt = 0; nt < 4; nt++) {
            f32x4 dw0 = __builtin_amdgcn_mfma_f32_16x16x32_bf16(xa[0][0], w2e[2 * nt], z4, 0, 0, 0);
            dw0 = __builtin_amdgcn_mfma_f32_16x16x32_bf16(xa[0][1], w2e[2 * nt + 1], dw0, 0, 0, 0);
            f32x4 dw1 = __builtin_amdgcn_mfma_f32_16x16x32_bf16(xa[1][0], w2e[2 * nt], z4, 0, 0, 0);
            dw1 = __builtin_amdgcn_mfma_f32_16x16x32_bf16(xa[1][1], w2e[2 * nt + 1], dw1, 0, 0, 0);
            i32x2 q0 = {pack2(dw0[0], dw0[1]), pack2(dw0[2], dw0[3])};
            i32x2 q1 = {pack2(dw1[0], dw1[1]), pack2(dw1[2], dw1[3])};
            *(i32x2*)(w0p + nt * 1024 + l15 * 64) = q0;
            *(i32x2*)(w1p + nt * 1024 + l15 * 64) = q1;
        }
        // W2^T frags hh=1 (hides under the wait + PV0)
        bf16x8 w2o[8];
        #pragma unroll
        for (int nt = 0; nt < 4; nt++) {
            int h = hp * 2 + 1;
            w2o[2 * nt]     = *(const bf16x8*)&w2f[((h * 4 + nt) * 2 + 0) * 512 + lane * 8];
            w2o[2 * nt + 1] = *(const bf16x8*)&w2f[((h * 4 + nt) * 2 + 1) * 512 + lane * 8];
        }
        LGKM0();   // P0/P1 + FWT(hh=0) visible

        // PV hh=0: acc += P0 @ FW0
        {
            bf16x8 ag0 = *(const bf16x8*)(pb0 + l15 * 80 + quad * 16);
            bf16x8 ag1 = *(const bf16x8*)(pb0 + (16 + l15) * 80 + quad * 16);
            #pragma unroll
            for (int nt = 0; nt < 4; nt++) {
                bf16x8 br = *(const bf16x8*)(brp + nt * 1024);
                acc[0][nt] = __builtin_amdgcn_mfma_f32_16x16x32_bf16(ag0, br, acc[0][nt], 0, 0, 0);
                acc[1][nt] = __builtin_amdgcn_mfma_f32_16x16x32_bf16(ag1, br, acc[1][nt], 0, 0, 0);
            }
        }

        // FW hh=1 -> FWT (after PV0's reads; same-wave DS ordering)
        #pragma unroll
        for (int nt = 0; nt < 4; nt++) {
            f32x4 dw0 = __builtin_amdgcn_mfma_f32_16x16x32_bf16(xa[0][0], w2o[2 * nt], z4, 0, 0, 0);
            dw0 = __builtin_amdgcn_mfma_f32_16x16x32_bf16(xa[0][1], w2o[2 * nt + 1], dw0, 0, 0, 0);
            f32x4 dw1 = __builtin_amdgcn_mfma_f32_16x16x32_bf16(xa[1][0], w2o[2 * nt], z4, 0, 0, 0);
            dw1 = __builtin_amdgcn_mfma_f32_16x16x32_bf16(xa[1][1], w2o[2 * nt + 1], dw1, 0, 0, 0);
            i32x2 q0 = {pack2(dw0[0], dw0[1]), pack2(dw0[2], dw0[3])};
            i32x2 q1 = {pack2(dw1[0], dw1[1]), pack2(dw1[2], dw1[3])};
            *(i32x2*)(w0p + nt * 1024 + l15 * 64) = q0;
            *(i32x2*)(w1p + nt * 1024 + l15 * 64) = q1;
        }
        LGKM0();   // FWT(hh=1) visible

        // PV hh=1: acc += P1 @ FW1
        {
            bf16x8 ag0 = *(const bf16x8*)(pb1 + l15 * 80 + quad * 16);
            bf16x8 ag1 = *(const bf16x8*)(pb1 + (16 + l15) * 80 + quad * 16);
            #pragma unroll
            for (int nt = 0; nt < 4; nt++) {
                bf16x8 br = *(const bf16x8*)(brp + nt * 1024);
                acc[0][nt] = __builtin_amdgcn_mfma_f32_16x16x32_bf16(ag0, br, acc[0][nt], 0, 0, 0);
                acc[1][nt] = __builtin_amdgcn_mfma_f32_16x16x32_bf16(ag1, br, acc[1][nt], 0, 0, 0);
            }
        }
    }

    // ---- epilogue: BN + residual + ReLU, direct global store ----
    #pragma unroll
    for (int nt = 0; nt < 4; nt++) {
        int o = nt * 16 + l15;
        float gA = bnA[o], gB = bnB[o];
        #pragma unroll
        for (int mt = 0; mt < 2; mt++) {
            int ub = mt * 16 + quad * 4;
            #pragma unroll
            for (int r = 0; r < 4; r++) {
                int u = ub + r;
                if (u < 25) {
                    float val = acc[mt][nt][r] * gA + gB + xg[o * 6400 + u];
                    og[o * 6400 + u] = fmaxf(val, 0.f);
                }
            }
        }
    }
}

extern "C" void kernel_launch(void* const* d_in, const int* in_sizes, int n_in,
                              void* d_out, int out_size, void* d_ws, size_t ws_size,
                              hipStream_t stream) {
    const float* x      = (const float*)d_in[0];
    const float* ln_g   = (const float*)d_in[1];
    const float* ln_b   = (const float*)d_in[2];
    const float* w_qk   = (const float*)d_in[3];
    const float* b_qk   = (const float*)d_in[4];
    const float* topo   = (const float*)d_in[5];
    const float* conv_w = (const float*)d_in[6];
    const float* conv_b = (const float*)d_in[7];
    const float* bn_g   = (const float*)d_in[8];
    const float* bn_b   = (const float*)d_in[9];
    const float* bn_m   = (const float*)d_in[10];
    const float* bn_v   = (const float*)d_in[11];
    float* outp = (float*)d_out;
    unsigned short* wsp = (unsigned short*)d_ws;

    hipLaunchKernelGGL(prep_kernel, dim3(161), dim3(256), 0, stream,
                       w_qk, conv_w, conv_b, bn_g, bn_b, bn_m, bn_v, wsp);
    hipLaunchKernelGGL(sagc_kernel, dim3(2048), dim3(256), 0, stream,
                       x, ln_g, ln_b, b_qk, topo, (const unsigned short*)wsp, outp);
}